// Round 1
// 86.835 us; speedup vs baseline: 1.1677x; 1.1677x over previous
//
#include <hip/hip_runtime.h>
#include <math.h>

#define BATCH  64
#define NNODE  1024
#define FDIM   64
#define DEG    8
#define ALPHA  0.2f
#define COPIES 4
#define RPB    (NNODE / COPIES)   // 256 output rows per block

typedef __attribute__((ext_vector_type(8))) short bf16x8;  // 8 bf16 in 4 VGPRs
typedef __attribute__((ext_vector_type(4))) float f32x4;

__device__ __forceinline__ short f2bf(float f) {
    union { float f; unsigned u; } v; v.f = f;
    unsigned r = v.u + 0x7fffu + ((v.u >> 16) & 1u);   // RNE
    return (short)(r >> 16);
}
__device__ __forceinline__ float bflo(unsigned d) {
    union { unsigned u; float f; } v; v.u = d << 16; return v.f;
}
__device__ __forceinline__ float bfhi(unsigned d) {
    union { unsigned u; float f; } v; v.u = d & 0xffff0000u; return v.f;
}

// One block = one (batch, quarter) pair. 1024 threads = 16 waves.
// Phase 1: full-batch h = atoms@W (bf16 MFMA) -> LDS (bf16, XOR-swizzled);
//          s1,s2 (f32, from f32 atoms) -> LDS.
// Phase 2: softmax weights for this quarter's 256 rows; store (packed gather
//          addr, weight) per edge.
// Phase 3: half-wave-per-row LDS gather-accumulate, ELU, coalesced store.
__global__ __launch_bounds__(1024) void gat_fused(
    const float* __restrict__ atoms,   // (B*N, 64) f32
    const int*   __restrict__ edges,   // (B*N, 8) int32
    const float* __restrict__ W,       // (64, 64) f32
    const float* __restrict__ a,       // (128,) f32
    float* __restrict__ out)           // (B*N, 64) f32
{
    __shared__ unsigned long long hsh[NNODE * FDIM / 4];  // 128KB swizzled bf16 h
    __shared__ float  s1l[NNODE];                         // 4KB
    __shared__ float  s2l[NNODE];                         // 4KB
    __shared__ float2 wal2[FDIM];                         // 512B  (wa1[k], wa2[k])
    __shared__ unsigned awl[RPB * DEG * 2];               // 16KB  (addr, weight)

    // XCD-bijective mapping: all 4 copies of batch b share bid%8 -> same XCD,
    // so atoms[b] (256KB) is HBM-fetched once and L2-hit by the other 3.
    const int bid = blockIdx.x;
    const int c = (bid >> 3) & 3;                       // copy 0..3
    const int b = (bid & 7) | ((bid >> 5) << 3);        // batch 0..63

    const int tid  = threadIdx.x;
    const int lane = tid & 63;
    const int wv   = tid >> 6;       // wave 0..15
    const int l16  = lane & 15;
    const int qd   = lane >> 4;

    // ---- wave 0: wa1/wa2 = W @ a1, W @ a2 (k0 folded in) ----
    if (wv == 0) {
        float p1 = 0.f, p2 = 0.f;
        #pragma unroll
        for (int j = 0; j < FDIM; ++j) {
            const float w = W[lane * FDIM + j];
            p1 = fmaf(w, a[j], p1);
            p2 = fmaf(w, a[FDIM + j], p2);
        }
        wal2[lane] = make_float2(p1, p2);
    }

    // ---- all waves: W fragments (A operand of transposed MFMA) ----
    // A[m=f=t*16+l16][k=ks*32+qd*8+j] = W[k][f]  (same lane map as k1's B-frag)
    bf16x8 Aw[2][4];
    #pragma unroll
    for (int ks = 0; ks < 2; ++ks)
        #pragma unroll
        for (int t = 0; t < 4; ++t)
            #pragma unroll
            for (int j = 0; j < 8; ++j)
                Aw[ks][t][j] = f2bf(W[(ks * 32 + qd * 8 + j) * FDIM + t * 16 + l16]);

    __syncthreads();   // wal2 ready

    float2 wv12[2][8];
    #pragma unroll
    for (int ks = 0; ks < 2; ++ks)
        #pragma unroll
        for (int j = 0; j < 8; ++j)
            wv12[ks][j] = wal2[ks * 32 + qd * 8 + j];

    // ---- phase 1: GEMM into LDS ----
    const float* __restrict__ ab = atoms + (size_t)b * NNODE * FDIM;
    #pragma unroll
    for (int tt = 0; tt < 4; ++tt) {
        const int node = wv * 64 + tt * 16 + l16;
        const float* __restrict__ ar = ab + (size_t)node * FDIM;

        bf16x8 Bv[2];
        float sp1 = 0.f, sp2 = 0.f;
        #pragma unroll
        for (int ks = 0; ks < 2; ++ks) {
            const float4 p0 = *(const float4*)(ar + ks * 32 + qd * 8);
            const float4 p1 = *(const float4*)(ar + ks * 32 + qd * 8 + 4);
            Bv[ks][0] = f2bf(p0.x); Bv[ks][1] = f2bf(p0.y);
            Bv[ks][2] = f2bf(p0.z); Bv[ks][3] = f2bf(p0.w);
            Bv[ks][4] = f2bf(p1.x); Bv[ks][5] = f2bf(p1.y);
            Bv[ks][6] = f2bf(p1.z); Bv[ks][7] = f2bf(p1.w);
            // f32 score partials (more accurate than old bf16-MFMA score path)
            sp1 = fmaf(p0.x, wv12[ks][0].x, sp1); sp2 = fmaf(p0.x, wv12[ks][0].y, sp2);
            sp1 = fmaf(p0.y, wv12[ks][1].x, sp1); sp2 = fmaf(p0.y, wv12[ks][1].y, sp2);
            sp1 = fmaf(p0.z, wv12[ks][2].x, sp1); sp2 = fmaf(p0.z, wv12[ks][2].y, sp2);
            sp1 = fmaf(p0.w, wv12[ks][3].x, sp1); sp2 = fmaf(p0.w, wv12[ks][3].y, sp2);
            sp1 = fmaf(p1.x, wv12[ks][4].x, sp1); sp2 = fmaf(p1.x, wv12[ks][4].y, sp2);
            sp1 = fmaf(p1.y, wv12[ks][5].x, sp1); sp2 = fmaf(p1.y, wv12[ks][5].y, sp2);
            sp1 = fmaf(p1.z, wv12[ks][6].x, sp1); sp2 = fmaf(p1.z, wv12[ks][6].y, sp2);
            sp1 = fmaf(p1.w, wv12[ks][7].x, sp1); sp2 = fmaf(p1.w, wv12[ks][7].y, sp2);
        }
        // reduce partial scores over qd (lanes l16, l16+16, l16+32, l16+48)
        sp1 += __shfl_xor(sp1, 16); sp1 += __shfl_xor(sp1, 32);
        sp2 += __shfl_xor(sp2, 16); sp2 += __shfl_xor(sp2, 32);
        if (qd == 0) { s1l[node] = sp1; s2l[node] = sp2; }

        // Transposed MFMA: D[m=f][n=node] -> each thread holds 4 consecutive f
        f32x4 C[4] = {{0,0,0,0},{0,0,0,0},{0,0,0,0},{0,0,0,0}};
        #pragma unroll
        for (int ks = 0; ks < 2; ++ks)
            #pragma unroll
            for (int t = 0; t < 4; ++t)
                C[t] = __builtin_amdgcn_mfma_f32_16x16x32_bf16(Aw[ks][t], Bv[ks], C[t], 0, 0, 0);

        // packed 8B swizzled write: f0 = t*16 + qd*4, node = col = l16 lane
        #pragma unroll
        for (int t = 0; t < 4; ++t) {
            union { unsigned short s[4]; unsigned long long v; } pk;
            pk.s[0] = (unsigned short)f2bf(C[t][0]);
            pk.s[1] = (unsigned short)f2bf(C[t][1]);
            pk.s[2] = (unsigned short)f2bf(C[t][2]);
            pk.s[3] = (unsigned short)f2bf(C[t][3]);
            const unsigned byte = (unsigned)node * 128u +
                (((unsigned)(t * 32 + qd * 8)) ^ ((unsigned)(node & 15) << 3));
            *(unsigned long long*)((char*)hsh + byte) = pk.v;
        }
    }
    __syncthreads();

    // ---- phase 2: softmax weights, (row,edge-pair)-parallel ----
    {
        const int r = tid >> 2;          // block-local row 0..255
        const int j = tid & 3;           // edge-pair 0..3
        const int grow = b * NNODE + c * RPB + r;
        const int2 ed = *(const int2*)(edges + (size_t)grow * DEG + 2 * j);

        // gather all 8 edge ids of the row across the 4-lane group
        const int ax = __shfl_xor(ed.x, 1), ay = __shfl_xor(ed.y, 1);
        const int bx = __shfl_xor(ed.x, 2), by = __shfl_xor(ed.y, 2);
        const int cx = __shfl_xor(ax, 2),   cy = __shfl_xor(ay, 2);

        int e8[8];
        #pragma unroll
        for (int o = 0; o < 4; ++o) {
            const int d = o ^ j;         // which register holds owner o's pair
            e8[2*o]   = (d == 0) ? ed.x : (d == 1) ? ax : (d == 2) ? bx : cx;
            e8[2*o+1] = (d == 0) ? ed.y : (d == 1) ? ay : (d == 2) ? by : cy;
        }

        const float s1v = s1l[c * RPB + r];
        float lA = s1v + s2l[ed.x];
        float lB = s1v + s2l[ed.y];
        lA = (lA > 0.f) ? lA : ALPHA * lA;   // LeakyReLU
        lB = (lB > 0.f) ? lB : ALPHA * lB;

        float m = fmaxf(lA, lB);
        m = fmaxf(m, __shfl_xor(m, 1));
        m = fmaxf(m, __shfl_xor(m, 2));

        // dedupe: adjacency is boolean, keep first occurrence only
        bool dupA = false, dupB = false;
        #pragma unroll
        for (int mm = 0; mm < 8; ++mm) {
            dupA = dupA || ((mm < 2 * j)     && (e8[mm] == ed.x));
            dupB = dupB || ((mm < 2 * j + 1) && (e8[mm] == ed.y));
        }

        float wA = dupA ? 0.f : __expf(lA - m);
        float wB = dupB ? 0.f : __expf(lB - m);
        float s = wA + wB;
        s += __shfl_xor(s, 1);
        s += __shfl_xor(s, 2);
        const float inv = 1.f / s;
        wA *= inv; wB *= inv;

        // packed gather base: low 7 bits = swizzle key, disjoint from row base
        union { float f; unsigned u; } fa, fb; fa.f = wA; fb.f = wB;
        uint4 st;
        st.x = (unsigned)(ed.x * 128 + ((ed.x & 15) << 3)); st.y = fa.u;
        st.z = (unsigned)(ed.y * 128 + ((ed.y & 15) << 3)); st.w = fb.u;
        *(uint4*)(awl + (r * DEG + 2 * j) * 2) = st;
    }
    __syncthreads();

    // ---- phase 3: half-wave-per-row gather-accumulate ----
    const int l32 = lane & 31;
    const int h32 = lane >> 5;
    float* __restrict__ ob = out + (size_t)(b * NNODE + c * RPB) * FDIM;
    #pragma unroll 2
    for (int p = 0; p < 8; ++p) {
        const int rowl = wv * 16 + 2 * p + h32;      // half-wave per row
        const uint2* __restrict__ awp = (const uint2*)(awl + rowl * DEG * 2);
        float a0 = 0.f, a1 = 0.f;
        #pragma unroll
        for (int k = 0; k < DEG; ++k) {
            const uint2 t = awp[k];                  // (packed addr, weight)
            const unsigned d = *(const unsigned*)((const char*)hsh +
                                   (t.x ^ (unsigned)(l32 << 2)));  // 1-XOR swizzled gather
            union { unsigned u; float f; } wu; wu.u = t.y;
            a0 = fmaf(wu.f, bflo(d), a0);            // col 2*l32
            a1 = fmaf(wu.f, bfhi(d), a1);            // col 2*l32+1
        }
        a0 = (a0 > 0.f) ? a0 : (__expf(a0) - 1.f);   // ELU
        a1 = (a1 > 0.f) ? a1 : (__expf(a1) - 1.f);
        *(float2*)(ob + (size_t)rowl * FDIM + 2 * l32) = make_float2(a0, a1);
    }
}

extern "C" void kernel_launch(void* const* d_in, const int* in_sizes, int n_in,
                              void* d_out, int out_size, void* d_ws, size_t ws_size,
                              hipStream_t stream) {
    const float* atoms = (const float*)d_in[0];   // (64,1024,64) f32
    const int*   edges = (const int*)d_in[1];     // (64,1024,8) int32
    const float* W     = (const float*)d_in[2];   // (64,64) f32
    const float* a     = (const float*)d_in[3];   // (128,1) f32
    float* out = (float*)d_out;                   // (64,1024,64) f32

    gat_fused<<<BATCH * COPIES, 1024, 0, stream>>>(atoms, edges, W, a, out);
}